// Round 3
// baseline (386.419 us; speedup 1.0000x reference)
//
#include <hip/hip_runtime.h>
#include <stdint.h>

// out[bm,q,h] = sum_k s[bm,q,k] * v[bm,k,h]
// bm=64, QT=KVT=1024, H=64, fp32 in/out. Memory-bound: ~302 MB HBM @ ~6.3 TB/s => ~48us floor.
// bf16 MFMA (2% tolerance). R3: A(s) fragments go global->regs->cvt->MFMA directly
// (MFMA A-layout is 8 consecutive k per lane = row-major friendly); only v is
// LDS-transposed (double-buffered, single barrier). Grid is (bm, qtile) so all
// q-tiles of one bm share an XCD's L2 copy of v[bm].

typedef __bf16 bf16x8 __attribute__((ext_vector_type(8)));
typedef float  f32x4  __attribute__((ext_vector_type(4)));
typedef uint32_t u32x4 __attribute__((ext_vector_type(4)));

#define QTDIM 1024
#define KVDIM 1024
#define HDIM  64
#define QTILE 64
#define BK    64
#define NK    (KVDIM / BK)   // 16
#define SSTR  72             // vt row stride (bf16 elems); 144 B rows, 16B-aligned
#define THREADS 256

// truncate two f32 to bf16, pack (hi<<16)|lo in one v_perm_b32
__device__ __forceinline__ uint32_t pack_bf16_2(float lo, float hi) {
    union { float f; uint32_t u; } a, b;
    a.f = lo; b.f = hi;
    return __builtin_amdgcn_perm(b.u, a.u, 0x07060302u);
}

__global__ __launch_bounds__(THREADS, 4) void svbmm_kernel(
    const float* __restrict__ s, const float* __restrict__ v, float* __restrict__ out)
{
    // only v^T tile in LDS: [h][k] bf16 [64][72], double-buffered (18.4 KB)
    __shared__ uint16_t vt_sm[2][HDIM * SSTR];

    const int tid = threadIdx.x;
    const int bm  = blockIdx.x;            // fast index -> all q-tiles of bm on one XCD
    const int q0  = blockIdx.y * QTILE;

    const float* sp = s   + ((size_t)bm * QTDIM + q0) * (size_t)KVDIM;
    const float* vp = v   + (size_t)bm * KVDIM * HDIM;
    float*       op = out + ((size_t)bm * QTDIM + q0) * (size_t)HDIM;

    const int wave = tid >> 6;   // wave owns q-rows [wave*16, wave*16+16)
    const int lane = tid & 63;
    const int lrow = lane & 15;
    const int quad = lane >> 4;

    // A: lane (lrow,quad) needs s[wave*16+lrow][kt*64 + kk*32 + quad*8 + 0..8)
    const float* ap = sp + (wave * 16 + lrow) * KVDIM + quad * 8;

    // v staging: lane-per-h (coalesced 256 B per wave instr), 16 k per thread
    const int vh  = tid & 63;
    const int vk0 = (tid >> 6) << 4;

    float4 a4[4];    // [kk*2+half]: k offsets {0,4,32,36}
    float  vreg[16];

    // prologue: tile 0 loads (v first: consumed first)
    {
        const float* vb = vp + vk0 * HDIM + vh;
        #pragma unroll
        for (int j = 0; j < 16; ++j)
            vreg[j] = vb[j * HDIM];
        #pragma unroll
        for (int i = 0; i < 4; ++i)
            a4[i] = *(const float4*)(ap + (i >> 1) * 32 + (i & 1) * 4);
    }

    f32x4 acc[4];
    #pragma unroll
    for (int nt = 0; nt < 4; ++nt)
        acc[nt] = (f32x4){0.f, 0.f, 0.f, 0.f};

    #pragma unroll 2
    for (int kt = 0; kt < NK; ++kt) {
        const int buf = kt & 1;

        // ---- 1. cvt v(kt) -> LDS (b64 stores) ----
        #pragma unroll
        for (int p = 0; p < 4; ++p) {
            uint64_t u = (uint64_t)pack_bf16_2(vreg[4 * p],     vreg[4 * p + 1])
                       | ((uint64_t)pack_bf16_2(vreg[4 * p + 2], vreg[4 * p + 3]) << 32);
            *(uint64_t*)&vt_sm[buf][vh * SSTR + vk0 + 4 * p] = u;
        }

        // ---- 2. single barrier (no fresh VMEM outstanding except old A, long
        //         since arrived => implicit vmcnt(0) is ~free) ----
        __syncthreads();

        // ---- 3. cvt A(kt) regs -> bf16 fragments ----
        bf16x8 afrag[2];
        #pragma unroll
        for (int kk = 0; kk < 2; ++kk) {
            union { u32x4 u; bf16x8 b; } fa;
            float4 lo = a4[kk * 2], hi = a4[kk * 2 + 1];
            fa.u[0] = pack_bf16_2(lo.x, lo.y);
            fa.u[1] = pack_bf16_2(lo.z, lo.w);
            fa.u[2] = pack_bf16_2(hi.x, hi.y);
            fa.u[3] = pack_bf16_2(hi.z, hi.w);
            afrag[kk] = fa.b;
        }

        // ---- 4. issue tile kt+1 loads (in flight across MFMA + back-edge) ----
        if (kt + 1 < NK) {
            const float* vb = vp + ((kt + 1) * BK + vk0) * HDIM + vh;
            #pragma unroll
            for (int j = 0; j < 16; ++j)
                vreg[j] = vb[j * HDIM];
            const float* ab = ap + (kt + 1) * BK;
            #pragma unroll
            for (int i = 0; i < 4; ++i)
                a4[i] = *(const float4*)(ab + (i >> 1) * 32 + (i & 1) * 4);
        }

        // ---- 5. MFMA on tile kt (B from LDS) ----
        #pragma unroll
        for (int kk = 0; kk < 2; ++kk) {
            const int col = kk * 32 + quad * 8;
            #pragma unroll
            for (int nt = 0; nt < 4; ++nt) {
                bf16x8 b = *(const bf16x8*)&vt_sm[buf][(nt * 16 + lrow) * SSTR + col];
                acc[nt] = __builtin_amdgcn_mfma_f32_16x16x32_bf16(afrag[kk], b, acc[nt], 0, 0, 0);
            }
        }
        // next iteration writes buf^1 whose readers finished before this barrier
    }

    // ---- epilogue: D layout row = quad*4 + r, col = lane&15 (m89/m91-verified) ----
    #pragma unroll
    for (int nt = 0; nt < 4; ++nt) {
        #pragma unroll
        for (int r = 0; r < 4; ++r) {
            const int row = wave * 16 + quad * 4 + r;
            const int col = nt * 16 + lrow;
            op[row * HDIM + col] = acc[nt][r];
        }
    }
}

extern "C" void kernel_launch(void* const* d_in, const int* in_sizes, int n_in,
                              void* d_out, int out_size, void* d_ws, size_t ws_size,
                              hipStream_t stream) {
    const float* s = (const float*)d_in[0];
    const float* v = (const float*)d_in[1];
    float* out = (float*)d_out;
    const int BM = in_sizes[0] / (QTDIM * KVDIM);  // 64
    dim3 grid(BM, QTDIM / QTILE);                  // bm fast -> same-XCD v reuse
    svbmm_kernel<<<grid, THREADS, 0, stream>>>(s, v, out);
}

// Round 4
// 383.162 us; speedup vs baseline: 1.0085x; 1.0085x over previous
//
#include <hip/hip_runtime.h>
#include <stdint.h>

// out[bm,q,h] = sum_k s[bm,q,k] * v[bm,k,h]
// bm=64, QT=KVT=1024, H=64, fp32 in/out. Memory-bound: ~302 MB HBM => ~48us floor.
// R4: R2's proven staging (s+v both through LDS, coalesced 256B segments) +
//   (a) bm-fast grid: all q-tiles of a bm land on XCD bm%8 -> v[bm] L2-resident
//   (b) 2-tile-ahead register prefetch + raw asm barrier (lgkmcnt only, NO
//       vmcnt(0) drain) so global loads stay in flight ~2 iterations ~ > HBM
//       latency. __syncthreads would drain vmcnt at every barrier (m97 stall).

typedef __bf16 bf16x8 __attribute__((ext_vector_type(8)));
typedef float  f32x4  __attribute__((ext_vector_type(4)));

#define QTDIM 1024
#define KVDIM 1024
#define HDIM  64
#define QTILE 64
#define BK    64
#define NK    (KVDIM / BK)   // 16
#define SSTR  72             // LDS row stride (bf16); 144 B rows, 16B-aligned
#define THREADS 256

// truncate two f32 to bf16, pack (hi<<16)|lo in one v_perm_b32
__device__ __forceinline__ uint32_t pack_bf16_2(float lo, float hi) {
    union { float f; uint32_t u; } a, b;
    a.f = lo; b.f = hi;
    return __builtin_amdgcn_perm(b.u, a.u, 0x07060302u);
}

// Workgroup barrier with LDS visibility but WITHOUT the vmcnt(0) drain that
// __syncthreads emits: in-flight global prefetch loads survive it. LDS is
// CU-local, so lgkmcnt(0) + s_barrier is sufficient for cross-wave LDS
// visibility; the outstanding global loads have no cross-wave consumers.
__device__ __forceinline__ void lds_barrier() {
    asm volatile("s_waitcnt lgkmcnt(0)\n\ts_barrier" ::: "memory");
}

__global__ __launch_bounds__(THREADS, 4) void svbmm_kernel(
    const float* __restrict__ s, const float* __restrict__ v, float* __restrict__ out)
{
    __shared__ uint16_t s_sm[2][QTILE * SSTR];   // bf16 s-tile [64][72] x2
    __shared__ uint16_t vt_sm[2][HDIM * SSTR];   // bf16 v^T [h][k] [64][72] x2

    const int tid = threadIdx.x;
    const int bm  = blockIdx.x;            // fast: q-tiles of bm share XCD bm%8
    const int q0  = blockIdx.y * QTILE;

    const float* sp = s   + ((size_t)bm * QTDIM + q0) * (size_t)KVDIM;
    const float* vp = v   + (size_t)bm * KVDIM * HDIM;
    float*       op = out + ((size_t)bm * QTDIM + q0) * (size_t)HDIM;

    // staging assignment (R2 pattern: 256B-contiguous per wave instruction)
    const int srow = tid >> 4;          // 0..15 (+16*i covers 64 rows)
    const int scol = (tid & 15) << 2;   // float4 col within BK
    const int vh   = tid & 63;          // h lane (contiguous in global v)
    const int vk0  = (tid >> 6) << 4;   // 0,16,32,48

    const int wave = tid >> 6;
    const int lane = tid & 63;
    const int lrow = lane & 15;
    const int quad = lane >> 4;

    float4 sregA[4], sregB[4];
    float  vregA[16], vregB[16];

    // prologue: tile 0 -> set A, tile 1 -> set B (both stay in flight)
    {
        const float* sb = sp + srow * KVDIM + scol;
        const float* vb = vp + vk0 * HDIM + vh;
        #pragma unroll
        for (int i = 0; i < 4; ++i) sregA[i] = *(const float4*)(sb + i * 16 * KVDIM);
        #pragma unroll
        for (int j = 0; j < 16; ++j) vregA[j] = vb[j * HDIM];
        sb += BK; vb += BK * HDIM;
        #pragma unroll
        for (int i = 0; i < 4; ++i) sregB[i] = *(const float4*)(sb + i * 16 * KVDIM);
        #pragma unroll
        for (int j = 0; j < 16; ++j) vregB[j] = vb[j * HDIM];
    }

    f32x4 acc[4];
    #pragma unroll
    for (int nt = 0; nt < 4; ++nt) acc[nt] = (f32x4){0.f, 0.f, 0.f, 0.f};

    // body: cvt(SET)->LDS[BUF]; barrier; issue loads KT+2 into SET; MFMA on BUF.
    // Safety of single barrier w/ dbuf: cvt(kt) writes BUF after barrier(kt-1),
    // which every wave crossed only after its MFMA(kt-2) reads of BUF.
#define BODY(KT, BUF, SR, VR)                                                   \
    do {                                                                        \
        _Pragma("unroll")                                                       \
        for (int i = 0; i < 4; ++i) {                                           \
            float4 f = SR[i];                                                   \
            uint64_t u = (uint64_t)pack_bf16_2(f.x, f.y)                        \
                       | ((uint64_t)pack_bf16_2(f.z, f.w) << 32);               \
            *(uint64_t*)&s_sm[BUF][(srow + i * 16) * SSTR + scol] = u;          \
        }                                                                       \
        _Pragma("unroll")                                                       \
        for (int p = 0; p < 4; ++p) {                                           \
            uint64_t u = (uint64_t)pack_bf16_2(VR[4 * p],     VR[4 * p + 1])    \
                       | ((uint64_t)pack_bf16_2(VR[4 * p + 2], VR[4 * p + 3]) << 32); \
            *(uint64_t*)&vt_sm[BUF][vh * SSTR + vk0 + 4 * p] = u;               \
        }                                                                       \
        lds_barrier();                                                          \
        if ((KT) + 2 < NK) {                                                    \
            const float* sb2 = sp + srow * KVDIM + ((KT) + 2) * BK + scol;      \
            _Pragma("unroll")                                                   \
            for (int i = 0; i < 4; ++i)                                         \
                SR[i] = *(const float4*)(sb2 + i * 16 * KVDIM);                 \
            const float* vb2 = vp + (((KT) + 2) * BK + vk0) * HDIM + vh;        \
            _Pragma("unroll")                                                   \
            for (int j = 0; j < 16; ++j)                                        \
                VR[j] = vb2[j * HDIM];                                          \
        }                                                                       \
        _Pragma("unroll")                                                       \
        for (int kk = 0; kk < 2; ++kk) {                                        \
            const int col = kk * 32 + quad * 8;                                 \
            bf16x8 a = *(const bf16x8*)&s_sm[BUF][(wave * 16 + lrow) * SSTR + col]; \
            _Pragma("unroll")                                                   \
            for (int nt = 0; nt < 4; ++nt) {                                    \
                bf16x8 b = *(const bf16x8*)&vt_sm[BUF][(nt * 16 + lrow) * SSTR + col]; \
                acc[nt] = __builtin_amdgcn_mfma_f32_16x16x32_bf16(a, b, acc[nt], 0, 0, 0); \
            }                                                                   \
        }                                                                       \
    } while (0)

    #pragma unroll 1
    for (int kt = 0; kt < NK; kt += 2) {
        BODY(kt,     0, sregA, vregA);
        BODY(kt + 1, 1, sregB, vregB);
    }
#undef BODY

    // epilogue: D layout row = quad*4 + r, col = lane&15 (m89/m91-verified)
    #pragma unroll
    for (int nt = 0; nt < 4; ++nt) {
        #pragma unroll
        for (int r = 0; r < 4; ++r) {
            const int row = wave * 16 + quad * 4 + r;
            const int col = nt * 16 + lrow;
            op[row * HDIM + col] = acc[nt][r];
        }
    }
}

extern "C" void kernel_launch(void* const* d_in, const int* in_sizes, int n_in,
                              void* d_out, int out_size, void* d_ws, size_t ws_size,
                              hipStream_t stream) {
    const float* s = (const float*)d_in[0];
    const float* v = (const float*)d_in[1];
    float* out = (float*)d_out;
    const int BM = in_sizes[0] / (QTDIM * KVDIM);  // 64
    dim3 grid(BM, QTDIM / QTILE);                  // bm fast -> same-XCD v reuse
    svbmm_kernel<<<grid, THREADS, 0, stream>>>(s, v, out);
}